// Round 1
// baseline (2633.745 us; speedup 1.0000x reference)
//
#include <hip/hip_runtime.h>
#include <math.h>

#define IN_C   128
#define OUT_C  64
#define CDIM   512
#define HW     128   // input spatial
#define OHW    256   // output spatial
#define NB     8     // batch

#define TS     16    // half-res tile side
#define ICB    8     // input channels staged per LDS pass
#define OCB    8     // output channels per block (chunk)

// ---------------- gain kernel: gain[n][ic] = 1 + tanh(c[n]·w_affine[ic]/sqrt(512) + b_affine[ic])
__global__ void gain_kernel(const float* __restrict__ c,
                            const float* __restrict__ w_affine,
                            const float* __restrict__ b_affine,
                            float* __restrict__ gain) {
    int wave = (blockIdx.x * blockDim.x + threadIdx.x) >> 6;  // 0..1023
    int lane = threadIdx.x & 63;
    if (wave >= NB * IN_C) return;
    int n  = wave >> 7;   // /128
    int ic = wave & 127;
    const float* cp = c + n * CDIM;
    const float* wp = w_affine + ic * CDIM;
    float s = 0.f;
    #pragma unroll
    for (int k = 0; k < CDIM / 64; ++k) s += cp[lane + 64 * k] * wp[lane + 64 * k];
    #pragma unroll
    for (int off = 32; off > 0; off >>= 1) s += __shfl_down(s, off);
    if (lane == 0) {
        float y = s * 0.04419417382415922f + b_affine[ic];   // 1/sqrt(512)
        gain[n * IN_C + ic] = 1.0f + tanhf(y);
    }
}

// ---------------- weight transform: Wp[ic][ky][kx][ph][oc], ph = py*2+px
// Wp = sum_{by,bx} w[oc][ic][2-by][2-bx] * k1[sy-by] * k1[sx-bx] / sqrt(1152)
// sy = 2*ky + (py==0), sx = 2*kx + (px==0), k1 = 2*f1 = {.25,.75,.75,.25}
__global__ void wprep_kernel(const float* __restrict__ w, float* __restrict__ wp) {
    int idx = blockIdx.x * blockDim.x + threadIdx.x;
    if (idx >= IN_C * 3 * 3 * 4 * OUT_C) return;
    int oc = idx & 63;
    int t  = idx >> 6;
    int ph = t & 3;  t >>= 2;
    int kx = t % 3;  t /= 3;
    int ky = t % 3;  t /= 3;
    int ic = t;
    int py = ph >> 1, px = ph & 1;
    int sy = 2 * ky + (py == 0 ? 1 : 0);
    int sx = 2 * kx + (px == 0 ? 1 : 0);
    const float k1[4] = {0.25f, 0.75f, 0.75f, 0.25f};
    float sum = 0.f;
    #pragma unroll
    for (int by = 0; by < 3; ++by) {
        int ay = sy - by;
        if (ay < 0 || ay > 3) continue;
        #pragma unroll
        for (int bx = 0; bx < 3; ++bx) {
            int ax = sx - bx;
            if (ax < 0 || ax > 3) continue;
            sum += w[((oc * IN_C + ic) * 3 + (2 - by)) * 3 + (2 - bx)] * k1[ay] * k1[ax];
        }
    }
    wp[idx] = sum * 0.029462782549439483f;   // 1/sqrt(1152)
}

__device__ inline float postact(float v) {
    v = v > 0.f ? v : 0.2f * v;
    v *= 1.4142135623730951f;
    return fminf(fmaxf(v, -256.f), 256.f);
}

// ---------------- main conv: out[n][oc][2y+py][2x+px] = sum_{ic,ky,kx} xg[n][ic][y+ky-1][x+kx-1]*Wp[ic][ky][kx][ph][oc]
__global__ __launch_bounds__(256) void conv_main(
    const float* __restrict__ x, const float* __restrict__ gain,
    const float* __restrict__ wp, const float* __restrict__ bias,
    float* __restrict__ out) {
    const int n    = blockIdx.z >> 3;
    const int occ  = (blockIdx.z & 7) * OCB;
    const int tx0  = blockIdx.x * TS;
    const int ty0  = blockIdx.y * TS;
    const int tid  = threadIdx.x;
    const int lx   = tid & 15;
    const int ly   = tid >> 4;

    __shared__ float xs[ICB][18][18];

    float acc[4][OCB];
    #pragma unroll
    for (int p = 0; p < 4; ++p)
        #pragma unroll
        for (int o = 0; o < OCB; ++o) acc[p][o] = 0.f;

    for (int ic0 = 0; ic0 < IN_C; ic0 += ICB) {
        __syncthreads();
        // stage ICB channels of the (18x18) halo tile, gain-scaled, zero-padded
        for (int i = tid; i < ICB * 324; i += 256) {
            int icb = i / 324;
            int rem = i - icb * 324;
            int yy  = rem / 18;
            int xx  = rem - yy * 18;
            int gy  = ty0 + yy - 1;
            int gx  = tx0 + xx - 1;
            int ic  = ic0 + icb;
            float v = 0.f;
            if (gy >= 0 && gy < HW && gx >= 0 && gx < HW)
                v = x[((n * IN_C + ic) * HW + gy) * HW + gx] * gain[n * IN_C + ic];
            xs[icb][yy][xx] = v;
        }
        __syncthreads();

        for (int icb = 0; icb < ICB; ++icb) {
            const int ic = ic0 + icb;
            float t[3][3];
            #pragma unroll
            for (int ky = 0; ky < 3; ++ky)
                #pragma unroll
                for (int kx = 0; kx < 3; ++kx)
                    t[ky][kx] = xs[icb][ly + ky][lx + kx];

            const float* wpp = wp + ic * (9 * 4 * OUT_C) + occ;
            #pragma unroll
            for (int ky = 0; ky < 3; ++ky)
                #pragma unroll
                for (int kx = 0; kx < 3; ++kx) {
                    const float* w9 = wpp + (ky * 3 + kx) * (4 * OUT_C);
                    #pragma unroll
                    for (int p = 0; p < 4; ++p)
                        #pragma unroll
                        for (int o = 0; o < OCB; ++o)
                            acc[p][o] = fmaf(t[ky][kx], w9[p * OUT_C + o], acc[p][o]);
                }
        }
    }

    // epilogue: bias + leaky_relu*sqrt2 + clamp; write float2 (px=0,1)
    const int ybase = 2 * (ty0 + ly);
    const int xbase = 2 * (tx0 + lx);
    #pragma unroll
    for (int o = 0; o < OCB; ++o) {
        float b = bias[occ + o];
        #pragma unroll
        for (int py = 0; py < 2; ++py) {
            float2 v;
            v.x = postact(acc[py * 2 + 0][o] + b);
            v.y = postact(acc[py * 2 + 1][o] + b);
            *reinterpret_cast<float2*>(
                &out[((size_t)(n * OUT_C + occ + o) * OHW + (ybase + py)) * OHW + xbase]) = v;
        }
    }
}

extern "C" void kernel_launch(void* const* d_in, const int* in_sizes, int n_in,
                              void* d_out, int out_size, void* d_ws, size_t ws_size,
                              hipStream_t stream) {
    const float* x        = (const float*)d_in[0];
    const float* c        = (const float*)d_in[1];
    const float* weight   = (const float*)d_in[2];
    const float* bias     = (const float*)d_in[3];
    const float* w_affine = (const float*)d_in[4];
    const float* b_affine = (const float*)d_in[5];
    float* out = (float*)d_out;

    float* gain = (float*)d_ws;                          // 8*128 floats
    float* wp   = (float*)((char*)d_ws + 8192);          // 294912 floats = 1.18MB

    gain_kernel<<<dim3((NB * IN_C * 64) / 256), dim3(256), 0, stream>>>(c, w_affine, b_affine, gain);
    wprep_kernel<<<dim3((IN_C * 9 * 4 * OUT_C + 255) / 256), dim3(256), 0, stream>>>(weight, wp);
    conv_main<<<dim3(HW / TS, HW / TS, NB * (OUT_C / OCB)), dim3(256), 0, stream>>>(x, gain, wp, bias, out);
}

// Round 2
// 176.502 us; speedup vs baseline: 14.9219x; 14.9219x over previous
//
#include <hip/hip_runtime.h>
#include <math.h>

#define IN_C   128
#define OUT_C  64
#define CDIM   512
#define HW     128   // input spatial (half-res)
#define OHW    256   // output spatial
#define NB     8     // batch

typedef __attribute__((ext_vector_type(8))) short short8;
typedef __attribute__((ext_vector_type(4))) float f32x4;

__device__ inline unsigned short f2bf(float f) {
    unsigned int u = __float_as_uint(f);
    unsigned int r = (u + 0x7fffu + ((u >> 16) & 1u)) >> 16;
    return (unsigned short)r;
}

__device__ inline float postact(float v) {
    v = v > 0.f ? v : 0.2f * v;
    v *= 1.4142135623730951f;
    return fminf(fmaxf(v, -256.f), 256.f);
}

// ---------------- gain: gain[n][ic] = 1 + tanh(c[n]·w_affine[ic]/sqrt(512) + b_affine[ic])
__global__ void gain_kernel(const float* __restrict__ c,
                            const float* __restrict__ w_affine,
                            const float* __restrict__ b_affine,
                            float* __restrict__ gain) {
    int wave = (blockIdx.x * blockDim.x + threadIdx.x) >> 6;
    int lane = threadIdx.x & 63;
    if (wave >= NB * IN_C) return;
    int n  = wave >> 7;
    int ic = wave & 127;
    const float* cp = c + n * CDIM;
    const float* wp = w_affine + ic * CDIM;
    float s = 0.f;
    #pragma unroll
    for (int k = 0; k < CDIM / 64; ++k) s += cp[lane + 64 * k] * wp[lane + 64 * k];
    #pragma unroll
    for (int off = 32; off > 0; off >>= 1) s += __shfl_down(s, off);
    if (lane == 0) {
        float y = s * 0.04419417382415922f + b_affine[ic];
        gain[n * IN_C + ic] = 1.0f + tanhf(y);
    }
}

// ---------------- Wb[tap][n=oc*4+ph][ic] bf16, all scales folded in
__global__ void wbprep_kernel(const float* __restrict__ w, unsigned short* __restrict__ wb) {
    int idx = blockIdx.x * blockDim.x + threadIdx.x;
    if (idx >= 9 * 256 * IN_C) return;
    int ic  = idx & 127;
    int n   = (idx >> 7) & 255;
    int tap = idx >> 15;
    int ky = tap / 3, kx = tap % 3;
    int oc = n >> 2, ph = n & 3;
    int py = ph >> 1, px = ph & 1;
    int sy = 2 * ky + (py == 0 ? 1 : 0);
    int sx = 2 * kx + (px == 0 ? 1 : 0);
    const float k1[4] = {0.25f, 0.75f, 0.75f, 0.25f};
    float sum = 0.f;
    #pragma unroll
    for (int by = 0; by < 3; ++by) {
        int ay = sy - by;
        if (ay < 0 || ay > 3) continue;
        #pragma unroll
        for (int bx = 0; bx < 3; ++bx) {
            int ax = sx - bx;
            if (ax < 0 || ax > 3) continue;
            sum += w[((oc * IN_C + ic) * 3 + (2 - by)) * 3 + (2 - bx)] * k1[ay] * k1[ax];
        }
    }
    wb[idx] = f2bf(sum * 0.029462782549439483f);   // 1/sqrt(1152)
}

// ---------------- xprep: xg[n][y][x][ic] = bf16(x[n][ic][y][x] * gain[n][ic])
__global__ __launch_bounds__(256) void xprep_kernel(const float* __restrict__ x,
                                                    const float* __restrict__ gain,
                                                    unsigned short* __restrict__ xg) {
    int n = blockIdx.x >> 7;
    int y = blockIdx.x & 127;
    __shared__ unsigned short lds[128][130];
    int tid = threadIdx.x;
    for (int i = tid; i < 128 * 128; i += 256) {
        int ic = i >> 7, pix = i & 127;
        float v = x[(((n * IN_C + ic) * HW) + y) * HW + pix] * gain[n * IN_C + ic];
        lds[pix][ic] = f2bf(v);
    }
    __syncthreads();
    unsigned int* dst = (unsigned int*)(xg + ((size_t)(n * HW + y) << 14));
    for (int i = tid; i < 8192; i += 256) {
        int pix = i >> 6, d = i & 63;
        dst[i] = *reinterpret_cast<const unsigned int*>(&lds[pix][d * 2]);
    }
}

// ---------------- main conv (MFMA): out = Wb @ xs per 16x8 half-res patch
// block: 512 threads = 8 waves; wave (wn,wr): wn in 0..3 -> n-group of 64, wr in 0..1 -> 4 pixel rows
__global__ __launch_bounds__(512, 4) void conv_mfma(
    const unsigned short* __restrict__ xg,
    const unsigned short* __restrict__ wb,
    const float* __restrict__ bias,
    float* __restrict__ out) {
    __shared__ __align__(16) unsigned char xs[46080];   // 10 rows x 18 cols x 128 ic x bf16
    const int n  = blockIdx.z;
    const int x0 = blockIdx.x * 16;
    const int y0 = blockIdx.y * 8;
    const int tid = threadIdx.x;

    // ---- stage halo tile, swizzled: addr = (row*18+col)<<8 | ((icb<<4) ^ ((col&7)<<4))
    const unsigned short* xbase = xg + ((size_t)n << 21);
    for (int cch = tid; cch < 2880; cch += 512) {
        int icb = cch & 15;
        int pc  = cch >> 4;          // 0..179
        int col = pc % 18;
        int row = pc / 18;
        int gy = y0 + row - 1, gx = x0 + col - 1;
        short8 v = (short8)(short)0;
        if ((unsigned)gy < 128u && (unsigned)gx < 128u)
            v = *reinterpret_cast<const short8*>(&xbase[(((gy << 7) + gx) << 7) + (icb << 3)]);
        int addr = (pc << 8) | (((icb << 4) ^ ((col & 7) << 4)));
        *reinterpret_cast<short8*>(&xs[addr]) = v;
    }
    __syncthreads();

    const int lane = tid & 63;
    const int w    = tid >> 6;
    const int wn   = w & 3;
    const int wr   = w >> 2;
    const int l16  = lane & 15;
    const int lhi  = lane >> 4;

    f32x4 acc[4][4];   // [pixel-row r][n-frag nf]
    #pragma unroll
    for (int r = 0; r < 4; ++r)
        #pragma unroll
        for (int f = 0; f < 4; ++f) acc[r][f] = (f32x4)0.f;

    // A per-lane base: Wb element (n = wn*64 + l16, ic = lhi*8)
    const unsigned short* apl = wb + ((wn * 64 + l16) * IN_C + lhi * 8);

    #pragma unroll 1
    for (int tap = 0; tap < 9; ++tap) {
        const int ky = tap / 3;
        const int kx = tap - ky * 3;
        const unsigned short* atap = apl + tap * (256 * IN_C);
        const int colt  = l16 + kx;
        const int rbase = ((wr * 4 + ky) * 18 + colt) << 8;
        const int bswz  = (colt & 7) << 4;
        #pragma unroll
        for (int kc = 0; kc < 4; ++kc) {
            short8 a0 = *reinterpret_cast<const short8*>(atap + kc * 32);
            short8 a1 = *reinterpret_cast<const short8*>(atap + kc * 32 + 2048);
            short8 a2 = *reinterpret_cast<const short8*>(atap + kc * 32 + 4096);
            short8 a3 = *reinterpret_cast<const short8*>(atap + kc * 32 + 6144);
            const int icoff = ((kc * 64 + lhi * 16) ^ bswz);
            short8 b0 = *reinterpret_cast<const short8*>(&xs[rbase + icoff]);
            short8 b1 = *reinterpret_cast<const short8*>(&xs[rbase + (18 << 8) + icoff]);
            short8 b2 = *reinterpret_cast<const short8*>(&xs[rbase + (36 << 8) + icoff]);
            short8 b3 = *reinterpret_cast<const short8*>(&xs[rbase + (54 << 8) + icoff]);
            acc[0][0] = __builtin_amdgcn_mfma_f32_16x16x32_bf16(a0, b0, acc[0][0], 0, 0, 0);
            acc[0][1] = __builtin_amdgcn_mfma_f32_16x16x32_bf16(a1, b0, acc[0][1], 0, 0, 0);
            acc[0][2] = __builtin_amdgcn_mfma_f32_16x16x32_bf16(a2, b0, acc[0][2], 0, 0, 0);
            acc[0][3] = __builtin_amdgcn_mfma_f32_16x16x32_bf16(a3, b0, acc[0][3], 0, 0, 0);
            acc[1][0] = __builtin_amdgcn_mfma_f32_16x16x32_bf16(a0, b1, acc[1][0], 0, 0, 0);
            acc[1][1] = __builtin_amdgcn_mfma_f32_16x16x32_bf16(a1, b1, acc[1][1], 0, 0, 0);
            acc[1][2] = __builtin_amdgcn_mfma_f32_16x16x32_bf16(a2, b1, acc[1][2], 0, 0, 0);
            acc[1][3] = __builtin_amdgcn_mfma_f32_16x16x32_bf16(a3, b1, acc[1][3], 0, 0, 0);
            acc[2][0] = __builtin_amdgcn_mfma_f32_16x16x32_bf16(a0, b2, acc[2][0], 0, 0, 0);
            acc[2][1] = __builtin_amdgcn_mfma_f32_16x16x32_bf16(a1, b2, acc[2][1], 0, 0, 0);
            acc[2][2] = __builtin_amdgcn_mfma_f32_16x16x32_bf16(a2, b2, acc[2][2], 0, 0, 0);
            acc[2][3] = __builtin_amdgcn_mfma_f32_16x16x32_bf16(a3, b2, acc[2][3], 0, 0, 0);
            acc[3][0] = __builtin_amdgcn_mfma_f32_16x16x32_bf16(a0, b3, acc[3][0], 0, 0, 0);
            acc[3][1] = __builtin_amdgcn_mfma_f32_16x16x32_bf16(a1, b3, acc[3][1], 0, 0, 0);
            acc[3][2] = __builtin_amdgcn_mfma_f32_16x16x32_bf16(a2, b3, acc[3][2], 0, 0, 0);
            acc[3][3] = __builtin_amdgcn_mfma_f32_16x16x32_bf16(a3, b3, acc[3][3], 0, 0, 0);
        }
    }

    // ---- epilogue: reg p of acc = phase p (py=p>>1, px=p&1); coalesced float2 stores
    #pragma unroll
    for (int f = 0; f < 4; ++f) {
        const int oc = wn * 16 + f * 4 + lhi;
        const float b = bias[oc];
        #pragma unroll
        for (int r = 0; r < 4; ++r) {
            const int ypix = y0 + wr * 4 + r;
            const int xpix = x0 + l16;
            float* o0 = out + (((size_t)(n * OUT_C + oc) * OHW) + 2 * ypix) * OHW + 2 * xpix;
            float2 v0 = make_float2(postact(acc[r][f][0] + b), postact(acc[r][f][1] + b));
            float2 v1 = make_float2(postact(acc[r][f][2] + b), postact(acc[r][f][3] + b));
            *reinterpret_cast<float2*>(o0) = v0;
            *reinterpret_cast<float2*>(o0 + OHW) = v1;
        }
    }
}

// ================= fallback f32 path (round-1, verified) =================
__global__ void wprep_kernel(const float* __restrict__ w, float* __restrict__ wp) {
    int idx = blockIdx.x * blockDim.x + threadIdx.x;
    if (idx >= IN_C * 9 * 4 * OUT_C) return;
    int oc = idx & 63;
    int t  = idx >> 6;
    int ph = t & 3;  t >>= 2;
    int kx = t % 3;  t /= 3;
    int ky = t % 3;  t /= 3;
    int ic = t;
    int py = ph >> 1, px = ph & 1;
    int sy = 2 * ky + (py == 0 ? 1 : 0);
    int sx = 2 * kx + (px == 0 ? 1 : 0);
    const float k1[4] = {0.25f, 0.75f, 0.75f, 0.25f};
    float sum = 0.f;
    #pragma unroll
    for (int by = 0; by < 3; ++by) {
        int ay = sy - by;
        if (ay < 0 || ay > 3) continue;
        #pragma unroll
        for (int bx = 0; bx < 3; ++bx) {
            int ax = sx - bx;
            if (ax < 0 || ax > 3) continue;
            sum += w[((oc * IN_C + ic) * 3 + (2 - by)) * 3 + (2 - bx)] * k1[ay] * k1[ax];
        }
    }
    wp[idx] = sum * 0.029462782549439483f;
}

__global__ __launch_bounds__(256) void conv_main(
    const float* __restrict__ x, const float* __restrict__ gain,
    const float* __restrict__ wp, const float* __restrict__ bias,
    float* __restrict__ out) {
    const int n    = blockIdx.z >> 3;
    const int occ  = (blockIdx.z & 7) * 8;
    const int tx0  = blockIdx.x * 16;
    const int ty0  = blockIdx.y * 16;
    const int tid  = threadIdx.x;
    const int lx   = tid & 15;
    const int ly   = tid >> 4;
    __shared__ float xsf[8][18][18];
    float acc[4][8];
    #pragma unroll
    for (int p = 0; p < 4; ++p)
        #pragma unroll
        for (int o = 0; o < 8; ++o) acc[p][o] = 0.f;
    for (int ic0 = 0; ic0 < IN_C; ic0 += 8) {
        __syncthreads();
        for (int i = tid; i < 8 * 324; i += 256) {
            int icb = i / 324;
            int rem = i - icb * 324;
            int yy  = rem / 18;
            int xx  = rem - yy * 18;
            int gy  = ty0 + yy - 1;
            int gx  = tx0 + xx - 1;
            int ic  = ic0 + icb;
            float v = 0.f;
            if (gy >= 0 && gy < HW && gx >= 0 && gx < HW)
                v = x[((n * IN_C + ic) * HW + gy) * HW + gx] * gain[n * IN_C + ic];
            xsf[icb][yy][xx] = v;
        }
        __syncthreads();
        for (int icb = 0; icb < 8; ++icb) {
            const int ic = ic0 + icb;
            const float* wpp = wp + ic * (9 * 4 * OUT_C) + occ;
            #pragma unroll
            for (int ky = 0; ky < 3; ++ky)
                #pragma unroll
                for (int kx = 0; kx < 3; ++kx) {
                    float t = xsf[icb][ly + ky][lx + kx];
                    const float* w9 = wpp + (ky * 3 + kx) * (4 * OUT_C);
                    #pragma unroll
                    for (int p = 0; p < 4; ++p)
                        #pragma unroll
                        for (int o = 0; o < 8; ++o)
                            acc[p][o] = fmaf(t, w9[p * OUT_C + o], acc[p][o]);
                }
        }
    }
    const int ybase = 2 * (ty0 + ly);
    const int xbase = 2 * (tx0 + lx);
    #pragma unroll
    for (int o = 0; o < 8; ++o) {
        float b = bias[occ + o];
        #pragma unroll
        for (int py = 0; py < 2; ++py) {
            float2 v;
            v.x = postact(acc[py * 2 + 0][o] + b);
            v.y = postact(acc[py * 2 + 1][o] + b);
            *reinterpret_cast<float2*>(
                &out[((size_t)(n * OUT_C + occ + o) * OHW + (ybase + py)) * OHW + xbase]) = v;
        }
    }
}

extern "C" void kernel_launch(void* const* d_in, const int* in_sizes, int n_in,
                              void* d_out, int out_size, void* d_ws, size_t ws_size,
                              hipStream_t stream) {
    const float* x        = (const float*)d_in[0];
    const float* c        = (const float*)d_in[1];
    const float* weight   = (const float*)d_in[2];
    const float* bias     = (const float*)d_in[3];
    const float* w_affine = (const float*)d_in[4];
    const float* b_affine = (const float*)d_in[5];
    float* out = (float*)d_out;

    float* gain = (float*)d_ws;   // 4 KB

    const size_t MFMA_WS = (size_t)1048576 + (size_t)NB * HW * HW * IN_C * 2;  // 34.5 MB
    if (ws_size >= MFMA_WS) {
        unsigned short* wbq = (unsigned short*)((char*)d_ws + 8192);      // 589824 B
        unsigned short* xg  = (unsigned short*)((char*)d_ws + 1048576);   // 33.5 MB
        gain_kernel<<<dim3((NB * IN_C * 64) / 256), dim3(256), 0, stream>>>(c, w_affine, b_affine, gain);
        wbprep_kernel<<<dim3((9 * 256 * IN_C + 255) / 256), dim3(256), 0, stream>>>(weight, wbq);
        xprep_kernel<<<dim3(NB * HW), dim3(256), 0, stream>>>(x, gain, xg);
        conv_mfma<<<dim3(HW / 16, HW / 8, NB), dim3(512), 0, stream>>>(xg, wbq, bias, out);
    } else {
        float* wp = (float*)((char*)d_ws + 8192);
        gain_kernel<<<dim3((NB * IN_C * 64) / 256), dim3(256), 0, stream>>>(c, w_affine, b_affine, gain);
        wprep_kernel<<<dim3((IN_C * 9 * 4 * OUT_C + 255) / 256), dim3(256), 0, stream>>>(weight, wp);
        conv_main<<<dim3(HW / 16, HW / 16, NB * 8), dim3(256), 0, stream>>>(x, gain, wp, bias, out);
    }
}

// Round 3
// 116.948 us; speedup vs baseline: 22.5207x; 1.5092x over previous
//
#include <hip/hip_runtime.h>
#include <math.h>

#define IN_C   128
#define OUT_C  64
#define CDIM   512
#define HW     128   // input spatial (half-res)
#define PHW    130   // padded
#define OHW    256   // output spatial
#define NB     8     // batch

typedef __attribute__((ext_vector_type(8))) short short8;
typedef __attribute__((ext_vector_type(4))) float f32x4;

__device__ inline unsigned short f2bf(float f) {
    unsigned int u = __float_as_uint(f);
    unsigned int r = (u + 0x7fffu + ((u >> 16) & 1u)) >> 16;
    return (unsigned short)r;
}

__device__ inline float postact(float v) {
    v = v > 0.f ? v : 0.2f * v;
    v *= 1.4142135623730951f;
    return fminf(fmaxf(v, -256.f), 256.f);
}

__device__ __forceinline__ void gload16(const void* g, void* l) {
    __builtin_amdgcn_global_load_lds(
        (const __attribute__((address_space(1))) unsigned int*)g,
        (__attribute__((address_space(3))) unsigned int*)l, 16, 0, 0);
}

// ---------------- gain: gain[n][ic] = 1 + tanh(c[n]·w_affine[ic]/sqrt(512) + b_affine[ic])
__global__ void gain_kernel(const float* __restrict__ c,
                            const float* __restrict__ w_affine,
                            const float* __restrict__ b_affine,
                            float* __restrict__ gain) {
    int wave = (blockIdx.x * blockDim.x + threadIdx.x) >> 6;
    int lane = threadIdx.x & 63;
    if (wave >= NB * IN_C) return;
    int n  = wave >> 7;
    int ic = wave & 127;
    const float* cp = c + n * CDIM;
    const float* wp = w_affine + ic * CDIM;
    float s = 0.f;
    #pragma unroll
    for (int k = 0; k < CDIM / 64; ++k) s += cp[lane + 64 * k] * wp[lane + 64 * k];
    #pragma unroll
    for (int off = 32; off > 0; off >>= 1) s += __shfl_down(s, off);
    if (lane == 0) {
        float y = s * 0.04419417382415922f + b_affine[ic];
        gain[n * IN_C + ic] = 1.0f + tanhf(y);
    }
}

// ---------------- weight transform into FRAGMENT-LINEAR layout:
// wb2 flat idx = kt*16384 + (kc*16+m16)*512 + lane*8 + e
// holds Wb[m = m16*16 + (lane&15)][ic = (kt&1)*64 + kc*32 + (lane>>4)*8 + e] for tap = kt>>1
__global__ void wbprep2_kernel(const float* __restrict__ w, unsigned short* __restrict__ wb2) {
    int idx = blockIdx.x * blockDim.x + threadIdx.x;
    if (idx >= 18 * 16384) return;
    int e    = idx & 7;
    int lane = (idx >> 3) & 63;
    int m16  = (idx >> 9) & 15;
    int kc   = (idx >> 13) & 1;
    int kt   = idx >> 14;            // 0..17
    int tap = kt >> 1, h = kt & 1;
    int m  = m16 * 16 + (lane & 15);
    int ic = h * 64 + kc * 32 + (lane >> 4) * 8 + e;
    int ky = tap / 3, kx = tap % 3;
    int oc = m >> 2, ph = m & 3;
    int py = ph >> 1, px = ph & 1;
    int sy = 2 * ky + (py == 0 ? 1 : 0);
    int sx = 2 * kx + (px == 0 ? 1 : 0);
    const float k1[4] = {0.25f, 0.75f, 0.75f, 0.25f};
    float sum = 0.f;
    #pragma unroll
    for (int by = 0; by < 3; ++by) {
        int ay = sy - by;
        if (ay < 0 || ay > 3) continue;
        #pragma unroll
        for (int bx = 0; bx < 3; ++bx) {
            int ax = sx - bx;
            if (ax < 0 || ax > 3) continue;
            sum += w[((oc * IN_C + ic) * 3 + (2 - by)) * 3 + (2 - bx)] * k1[ay] * k1[ax];
        }
    }
    wb2[idx] = f2bf(sum * 0.029462782549439483f);   // 1/sqrt(1152)
}

// ---------------- xprep: xg[n][y+1][x+1][ic] = bf16(x[n][ic][y][x] * gain[n][ic]); padded 130x130
__global__ __launch_bounds__(256) void xprep_kernel(const float* __restrict__ x,
                                                    const float* __restrict__ gain,
                                                    unsigned short* __restrict__ xg) {
    int n = blockIdx.x >> 7;
    int y = blockIdx.x & 127;
    __shared__ unsigned short lds[128][130];
    int tid = threadIdx.x;
    for (int i = tid; i < 128 * 128; i += 256) {
        int ic = i >> 7, pix = i & 127;
        float v = x[(((n * IN_C + ic) * HW) + y) * HW + pix] * gain[n * IN_C + ic];
        lds[pix][ic] = f2bf(v);
    }
    __syncthreads();
    unsigned int* dst = (unsigned int*)(xg + (((size_t)(n * PHW) + y + 1) * PHW + 1) * 128);
    for (int i = tid; i < 8192; i += 256) {
        int pix = i >> 6, d = i & 63;
        dst[pix * 64 + d] = *reinterpret_cast<const unsigned int*>(&lds[pix][d * 2]);
    }
}

// ---------------- zero the padded border of xg (must run every call; ws not re-poisoned)
__global__ void border_kernel(unsigned short* __restrict__ xg) {
    int id = blockIdx.x * blockDim.x + threadIdx.x;   // 8*516*16
    int c = id & 15;
    int t = id >> 4;
    int p = t % 516;
    int n = t / 516;
    if (n >= NB) return;
    int Y, X;
    if (p < 130)      { Y = 0;   X = p; }
    else if (p < 260) { Y = 129; X = p - 130; }
    else              { int q = p - 260; Y = 1 + (q >> 1); X = (q & 1) * 129; }
    uint4 z = make_uint4(0, 0, 0, 0);
    *reinterpret_cast<uint4*>(xg + (((size_t)(n * PHW) + Y) * PHW + X) * 128 + c * 8) = z;
}

// ---------------- main conv: M=256 (oc*4+ph) x N=256 px patch x K=1152, BK=64, 18 K-steps
// 8 waves = 2M x 4N; per-wave 128x64; double-buffered LDS 128KB; counted vmcnt; 4 phases/K-step
#define BARRIER() do { __builtin_amdgcn_sched_barrier(0); __builtin_amdgcn_s_barrier(); __builtin_amdgcn_sched_barrier(0); } while (0)
#define MM(ACC, AF, BF) ACC = __builtin_amdgcn_mfma_f32_16x16x32_bf16(AF, BF, ACC, 0, 0, 0)

__global__ __launch_bounds__(512) void conv_mfma2(
    const unsigned short* __restrict__ xg,
    const unsigned short* __restrict__ wb2,
    const float* __restrict__ bias,
    float* __restrict__ out) {
    __shared__ __align__(16) char smem[131072];   // 2 x (A 32KB + B 32KB)

    const int bid = blockIdx.x;        // 512 blocks
    const int n     = bid >> 6;
    const int patch = bid & 63;
    const int y0 = (patch >> 3) * 16;
    const int x0 = (patch & 7) * 16;
    const int tid  = threadIdx.x;
    const int lane = tid & 63;
    const int wid  = tid >> 6;
    const int wM = wid >> 2;           // 0..1
    const int wN = wid & 3;            // 0..3
    const int l16 = lane & 15;
    const int lhi = lane >> 4;
    const int mbase = wM * 8;
    const int pbase = wN * 4;

    // per-thread staging constants (4 rounds of 16B per operand)
    int ldsoff[4]; int aoff[4]; size_t boff[4];
    #pragma unroll
    for (int r = 0; r < 4; ++r) {
        int slot = r * 512 + tid;
        ldsoff[r] = (r * 512 + wid * 64) * 16;    // wave-uniform LDS base (HW adds lane*16)
        aoff[r] = slot * 8;
        int px = slot >> 3, j = slot & 7, s = j ^ (px & 7);
        boff[r] = (((size_t)(n * PHW) + y0 + (px >> 4)) * PHW + (x0 + (px & 15))) * 128 + s * 8;
    }

    auto stage = [&](int k, int p) {
        int tap = k >> 1, h = k & 1;
        int ky = tap / 3, kx = tap - ky * 3;
        int toff = (ky * PHW + kx) * 128 + h * 64;
        const unsigned short* aS = wb2 + k * 16384;
        char* bufA = smem + (p << 16);
        #pragma unroll
        for (int r = 0; r < 4; ++r) gload16(aS + aoff[r], bufA + ldsoff[r]);
        #pragma unroll
        for (int r = 0; r < 4; ++r) gload16(xg + boff[r] + toff, bufA + 32768 + ldsoff[r]);
    };

    f32x4 acc[8][4];
    #pragma unroll
    for (int f = 0; f < 8; ++f)
        #pragma unroll
        for (int b = 0; b < 4; ++b) acc[f][b] = (f32x4)0.f;

    // prologue: stage K-step 0 -> buf0, K-step 1 -> buf1
    stage(0, 0);
    stage(1, 1);

    #pragma unroll 1
    for (int t = 0; t < 18; ++t) {
        const int p = t & 1;
        const char* bA = smem + (p << 16);
        const char* bB = bA + 32768;

        if (t >= 1 && t < 17) stage(t + 1, (t + 1) & 1);   // buf freed by end of tile t-1
        if (t < 17) { asm volatile("s_waitcnt vmcnt(8)" ::: "memory"); }
        else        { asm volatile("s_waitcnt vmcnt(0)" ::: "memory"); }
        BARRIER();   // tile t fully resident for all waves

        auto ldA = [&](int f, int kc) -> short8 {
            return *reinterpret_cast<const short8*>(bA + (((kc << 4) + mbase + f) << 10) + (lane << 4));
        };
        auto ldB = [&](int b, int kc) -> short8 {
            int px = ((pbase + b) << 4) + l16;
            int off = (((kc << 6) + (lhi << 4)) ^ ((px & 7) << 4));
            return *reinterpret_cast<const short8*>(bB + (px << 7) + off);
        };

        short8 A0[4][2], A1[4][2], B0[2][2], B1[2][2];

        // ---- phase 0: (M0, N0)
        #pragma unroll
        for (int f = 0; f < 4; ++f) { A0[f][0] = ldA(f, 0); A0[f][1] = ldA(f, 1); }
        #pragma unroll
        for (int b = 0; b < 2; ++b) { B0[b][0] = ldB(b, 0); B0[b][1] = ldB(b, 1); }
        BARRIER();
        __builtin_amdgcn_s_setprio(1);
        #pragma unroll
        for (int f = 0; f < 4; ++f)
            #pragma unroll
            for (int b = 0; b < 2; ++b) { MM(acc[f][b], A0[f][0], B0[b][0]); MM(acc[f][b], A0[f][1], B0[b][1]); }
        __builtin_amdgcn_s_setprio(0);
        BARRIER();

        // ---- phase 1: (M0, N1)
        #pragma unroll
        for (int b = 0; b < 2; ++b) { B1[b][0] = ldB(b + 2, 0); B1[b][1] = ldB(b + 2, 1); }
        BARRIER();
        __builtin_amdgcn_s_setprio(1);
        #pragma unroll
        for (int f = 0; f < 4; ++f)
            #pragma unroll
            for (int b = 0; b < 2; ++b) { MM(acc[f][b + 2], A0[f][0], B1[b][0]); MM(acc[f][b + 2], A0[f][1], B1[b][1]); }
        __builtin_amdgcn_s_setprio(0);
        BARRIER();

        // ---- phase 2: (M1, N0)
        #pragma unroll
        for (int f = 0; f < 4; ++f) { A1[f][0] = ldA(4 + f, 0); A1[f][1] = ldA(4 + f, 1); }
        BARRIER();
        __builtin_amdgcn_s_setprio(1);
        #pragma unroll
        for (int f = 0; f < 4; ++f)
            #pragma unroll
            for (int b = 0; b < 2; ++b) { MM(acc[4 + f][b], A1[f][0], B0[b][0]); MM(acc[4 + f][b], A1[f][1], B0[b][1]); }
        __builtin_amdgcn_s_setprio(0);
        BARRIER();

        // ---- phase 3: (M1, N1) — no new reads
        __builtin_amdgcn_s_setprio(1);
        #pragma unroll
        for (int f = 0; f < 4; ++f)
            #pragma unroll
            for (int b = 0; b < 2; ++b) { MM(acc[4 + f][b + 2], A1[f][0], B1[b][0]); MM(acc[4 + f][b + 2], A1[f][1], B1[b][1]); }
        __builtin_amdgcn_s_setprio(0);
        BARRIER();
    }

    // ---- epilogue: m = wM*128 + f*16 + lhi*4 + r; oc = m>>2, phase = m&3 = r
    #pragma unroll
    for (int f = 0; f < 8; ++f) {
        const int oc = wM * 32 + f * 4 + lhi;
        const float bi = bias[oc];
        #pragma unroll
        for (int b = 0; b < 4; ++b) {
            const int ypix = y0 + pbase + b;
            const int xpix = x0 + l16;
            float* o0 = out + (((size_t)(n * OUT_C + oc) * OHW) + 2 * ypix) * OHW + 2 * xpix;
            float2 v0 = make_float2(postact(acc[f][b][0] + bi), postact(acc[f][b][1] + bi));
            float2 v1 = make_float2(postact(acc[f][b][2] + bi), postact(acc[f][b][3] + bi));
            *reinterpret_cast<float2*>(o0) = v0;
            *reinterpret_cast<float2*>(o0 + OHW) = v1;
        }
    }
}

// ================= fallback f32 path (round-1, verified) =================
__global__ void wprep_kernel(const float* __restrict__ w, float* __restrict__ wp) {
    int idx = blockIdx.x * blockDim.x + threadIdx.x;
    if (idx >= IN_C * 9 * 4 * OUT_C) return;
    int oc = idx & 63;
    int t  = idx >> 6;
    int ph = t & 3;  t >>= 2;
    int kx = t % 3;  t /= 3;
    int ky = t % 3;  t /= 3;
    int ic = t;
    int py = ph >> 1, px = ph & 1;
    int sy = 2 * ky + (py == 0 ? 1 : 0);
    int sx = 2 * kx + (px == 0 ? 1 : 0);
    const float k1[4] = {0.25f, 0.75f, 0.75f, 0.25f};
    float sum = 0.f;
    #pragma unroll
    for (int by = 0; by < 3; ++by) {
        int ay = sy - by;
        if (ay < 0 || ay > 3) continue;
        #pragma unroll
        for (int bx = 0; bx < 3; ++bx) {
            int ax = sx - bx;
            if (ax < 0 || ax > 3) continue;
            sum += w[((oc * IN_C + ic) * 3 + (2 - by)) * 3 + (2 - bx)] * k1[ay] * k1[ax];
        }
    }
    wp[idx] = sum * 0.029462782549439483f;
}

__global__ __launch_bounds__(256) void conv_main(
    const float* __restrict__ x, const float* __restrict__ gain,
    const float* __restrict__ wp, const float* __restrict__ bias,
    float* __restrict__ out) {
    const int n    = blockIdx.z >> 3;
    const int occ  = (blockIdx.z & 7) * 8;
    const int tx0  = blockIdx.x * 16;
    const int ty0  = blockIdx.y * 16;
    const int tid  = threadIdx.x;
    const int lx   = tid & 15;
    const int ly   = tid >> 4;
    __shared__ float xsf[8][18][18];
    float acc[4][8];
    #pragma unroll
    for (int p = 0; p < 4; ++p)
        #pragma unroll
        for (int o = 0; o < 8; ++o) acc[p][o] = 0.f;
    for (int ic0 = 0; ic0 < IN_C; ic0 += 8) {
        __syncthreads();
        for (int i = tid; i < 8 * 324; i += 256) {
            int icb = i / 324;
            int rem = i - icb * 324;
            int yy  = rem / 18;
            int xx  = rem - yy * 18;
            int gy  = ty0 + yy - 1;
            int gx  = tx0 + xx - 1;
            int ic  = ic0 + icb;
            float v = 0.f;
            if (gy >= 0 && gy < HW && gx >= 0 && gx < HW)
                v = x[((n * IN_C + ic) * HW + gy) * HW + gx] * gain[n * IN_C + ic];
            xsf[icb][yy][xx] = v;
        }
        __syncthreads();
        for (int icb = 0; icb < 8; ++icb) {
            const int ic = ic0 + icb;
            const float* wpp = wp + ic * (9 * 4 * OUT_C) + occ;
            #pragma unroll
            for (int ky = 0; ky < 3; ++ky)
                #pragma unroll
                for (int kx = 0; kx < 3; ++kx) {
                    float tv = xsf[icb][ly + ky][lx + kx];
                    const float* w9 = wpp + (ky * 3 + kx) * (4 * OUT_C);
                    #pragma unroll
                    for (int p = 0; p < 4; ++p)
                        #pragma unroll
                        for (int o = 0; o < 8; ++o)
                            acc[p][o] = fmaf(tv, w9[p * OUT_C + o], acc[p][o]);
                }
        }
    }
    const int ybase = 2 * (ty0 + ly);
    const int xbase = 2 * (tx0 + lx);
    #pragma unroll
    for (int o = 0; o < 8; ++o) {
        float b = bias[occ + o];
        #pragma unroll
        for (int py = 0; py < 2; ++py) {
            float2 v;
            v.x = postact(acc[py * 2 + 0][o] + b);
            v.y = postact(acc[py * 2 + 1][o] + b);
            *reinterpret_cast<float2*>(
                &out[((size_t)(n * OUT_C + occ + o) * OHW + (ybase + py)) * OHW + xbase]) = v;
        }
    }
}

extern "C" void kernel_launch(void* const* d_in, const int* in_sizes, int n_in,
                              void* d_out, int out_size, void* d_ws, size_t ws_size,
                              hipStream_t stream) {
    const float* x        = (const float*)d_in[0];
    const float* c        = (const float*)d_in[1];
    const float* weight   = (const float*)d_in[2];
    const float* bias     = (const float*)d_in[3];
    const float* w_affine = (const float*)d_in[4];
    const float* b_affine = (const float*)d_in[5];
    float* out = (float*)d_out;

    float* gain = (float*)d_ws;   // 4 KB @ 0

    const size_t NEED = 1048576 + (size_t)NB * PHW * PHW * IN_C * 2;  // ~35.7 MB
    if (ws_size >= NEED) {
        unsigned short* wb2 = (unsigned short*)((char*)d_ws + 8192);      // 589824 B
        unsigned short* xg  = (unsigned short*)((char*)d_ws + 1048576);   // 34.6 MB padded NHWC
        gain_kernel<<<dim3((NB * IN_C * 64) / 256), dim3(256), 0, stream>>>(c, w_affine, b_affine, gain);
        wbprep2_kernel<<<dim3((18 * 16384) / 256), dim3(256), 0, stream>>>(weight, wb2);
        xprep_kernel<<<dim3(NB * HW), dim3(256), 0, stream>>>(x, gain, xg);
        border_kernel<<<dim3((NB * 516 * 16) / 256), dim3(256), 0, stream>>>(xg);
        conv_mfma2<<<dim3(512), dim3(512), 0, stream>>>(xg, wb2, bias, out);
    } else {
        float* wp = (float*)((char*)d_ws + 8192);
        gain_kernel<<<dim3((NB * IN_C * 64) / 256), dim3(256), 0, stream>>>(c, w_affine, b_affine, gain);
        wprep_kernel<<<dim3((IN_C * 9 * 4 * OUT_C + 255) / 256), dim3(256), 0, stream>>>(weight, wp);
        conv_main<<<dim3(HW / 16, HW / 16, NB * 8), dim3(256), 0, stream>>>(x, gain, wp, bias, out);
    }
}

// Round 4
// 111.640 us; speedup vs baseline: 23.5914x; 1.0475x over previous
//
#include <hip/hip_runtime.h>
#include <math.h>

#define IN_C   128
#define OUT_C  64
#define CDIM   512
#define HW     128   // input spatial (half-res)
#define PHW    130   // padded
#define OHW    256   // output spatial
#define NB     8     // batch

typedef __attribute__((ext_vector_type(8))) short short8;
typedef __attribute__((ext_vector_type(4))) float f32x4;

__device__ inline unsigned short f2bf(float f) {
    unsigned int u = __float_as_uint(f);
    unsigned int r = (u + 0x7fffu + ((u >> 16) & 1u)) >> 16;
    return (unsigned short)r;
}

__device__ inline float postact(float v) {
    v = v > 0.f ? v : 0.2f * v;
    v *= 1.4142135623730951f;
    return fminf(fmaxf(v, -256.f), 256.f);
}

__device__ __forceinline__ void gload16(const void* g, void* l) {
    __builtin_amdgcn_global_load_lds(
        (const __attribute__((address_space(1))) unsigned int*)g,
        (__attribute__((address_space(3))) unsigned int*)l, 16, 0, 0);
}

// ---------------- gain: gain[n][ic] = 1 + tanh(c[n]·w_affine[ic]/sqrt(512) + b_affine[ic])
__global__ void gain_kernel(const float* __restrict__ c,
                            const float* __restrict__ w_affine,
                            const float* __restrict__ b_affine,
                            float* __restrict__ gain) {
    int wave = (blockIdx.x * blockDim.x + threadIdx.x) >> 6;
    int lane = threadIdx.x & 63;
    if (wave >= NB * IN_C) return;
    int n  = wave >> 7;
    int ic = wave & 127;
    const float* cp = c + n * CDIM;
    const float* wp = w_affine + ic * CDIM;
    float s = 0.f;
    #pragma unroll
    for (int k = 0; k < CDIM / 64; ++k) s += cp[lane + 64 * k] * wp[lane + 64 * k];
    #pragma unroll
    for (int off = 32; off > 0; off >>= 1) s += __shfl_down(s, off);
    if (lane == 0) {
        float y = s * 0.04419417382415922f + b_affine[ic];
        gain[n * IN_C + ic] = 1.0f + tanhf(y);
    }
}

// ---------------- weight transform into FRAGMENT-LINEAR layout:
// wb2 flat idx = kt*16384 + (kc*16+m16)*512 + lane*8 + e
// holds Wb[m = m16*16 + (lane&15)][ic = (kt&1)*64 + kc*32 + (lane>>4)*8 + e] for tap = kt>>1
__global__ void wbprep2_kernel(const float* __restrict__ w, unsigned short* __restrict__ wb2) {
    int idx = blockIdx.x * blockDim.x + threadIdx.x;
    if (idx >= 18 * 16384) return;
    int e    = idx & 7;
    int lane = (idx >> 3) & 63;
    int m16  = (idx >> 9) & 15;
    int kc   = (idx >> 13) & 1;
    int kt   = idx >> 14;            // 0..17
    int tap = kt >> 1, h = kt & 1;
    int m  = m16 * 16 + (lane & 15);
    int ic = h * 64 + kc * 32 + (lane >> 4) * 8 + e;
    int ky = tap / 3, kx = tap % 3;
    int oc = m >> 2, ph = m & 3;
    int py = ph >> 1, px = ph & 1;
    int sy = 2 * ky + (py == 0 ? 1 : 0);
    int sx = 2 * kx + (px == 0 ? 1 : 0);
    const float k1[4] = {0.25f, 0.75f, 0.75f, 0.25f};
    float sum = 0.f;
    #pragma unroll
    for (int by = 0; by < 3; ++by) {
        int ay = sy - by;
        if (ay < 0 || ay > 3) continue;
        #pragma unroll
        for (int bx = 0; bx < 3; ++bx) {
            int ax = sx - bx;
            if (ax < 0 || ax > 3) continue;
            sum += w[((oc * IN_C + ic) * 3 + (2 - by)) * 3 + (2 - bx)] * k1[ay] * k1[ax];
        }
    }
    wb2[idx] = f2bf(sum * 0.029462782549439483f);   // 1/sqrt(1152)
}

// ---------------- xprep: padded 130x130 NHWC bf16, ic-chunk order XOR-swizzled by (X&7)
// chunk j (16B) of pixel at padded col X stored at position j ^ (X&7)  (j=0..7 within each 128B half? no: j=0..15, key<8)
__global__ __launch_bounds__(256) void xprep_kernel(const float* __restrict__ x,
                                                    const float* __restrict__ gain,
                                                    unsigned short* __restrict__ xg) {
    int n = blockIdx.x >> 7;
    int y = blockIdx.x & 127;
    __shared__ unsigned short lds[128][130];
    int tid = threadIdx.x;
    for (int i = tid; i < 128 * 128; i += 256) {
        int ic = i >> 7, pix = i & 127;
        float v = x[(((n * IN_C + ic) * HW) + y) * HW + pix] * gain[n * IN_C + ic];
        lds[pix][ic] = f2bf(v);
    }
    __syncthreads();
    unsigned int* dst = (unsigned int*)(xg + (((size_t)(n * PHW) + y + 1) * PHW + 1) * 128);
    for (int i = tid; i < 8192; i += 256) {
        int pix = i >> 6, d = i & 63;
        int j = d >> 2, w = d & 3;
        int js = j ^ ((pix + 1) & 7);          // swizzle key = padded X & 7
        dst[pix * 64 + js * 4 + w] = *reinterpret_cast<const unsigned int*>(&lds[pix][d * 2]);
    }
}

// ---------------- zero the padded border of xg (zeros are swizzle-invariant)
__global__ void border_kernel(unsigned short* __restrict__ xg) {
    int id = blockIdx.x * blockDim.x + threadIdx.x;   // 8*516*16
    int c = id & 15;
    int t = id >> 4;
    int p = t % 516;
    int n = t / 516;
    if (n >= NB) return;
    int Y, X;
    if (p < 130)      { Y = 0;   X = p; }
    else if (p < 260) { Y = 129; X = p - 130; }
    else              { int q = p - 260; Y = 1 + (q >> 1); X = (q & 1) * 129; }
    uint4 z = make_uint4(0, 0, 0, 0);
    *reinterpret_cast<uint4*>(xg + (((size_t)(n * PHW) + Y) * PHW + X) * 128 + c * 8) = z;
}

// ---------------- main conv: M=256 x N=256px x K=1152. B halo (18x18x128) LDS-resident,
// A double-buffered 2x32KB, 18 K-steps, 2 barriers + vmcnt(4) per step.
#define BARRIER() do { __builtin_amdgcn_sched_barrier(0); __builtin_amdgcn_s_barrier(); __builtin_amdgcn_sched_barrier(0); } while (0)
#define MM(ACC, AF, BF) ACC = __builtin_amdgcn_mfma_f32_16x16x32_bf16(AF, BF, ACC, 0, 0, 0)

__global__ __launch_bounds__(512) void conv_mfma3(
    const unsigned short* __restrict__ xg,
    const unsigned short* __restrict__ wb2,
    const float* __restrict__ bias,
    float* __restrict__ out) {
    // A dbuf: [0, 65536) ; B halo: [65536, 65536+82944)
    __shared__ __align__(16) char smem[148480];

    const int bid   = blockIdx.x;      // 512 blocks
    const int n     = bid >> 6;
    const int patch = bid & 63;
    const int Y0 = (patch >> 3) * 16;  // halo origin in padded coords (== patch origin half-res)
    const int X0 = (patch & 7) * 16;   // multiple of 16 -> swizzle key block-independent
    const int tid  = threadIdx.x;
    const int lane = tid & 63;
    const int wid  = tid >> 6;
    const int wM = wid >> 2;           // 0..1
    const int wN = wid & 3;            // 0..3
    const int l16 = lane & 15;
    const int lhi = lane >> 4;
    const int mbase = wM * 8;
    const int pbase = wN * 4;

    const char* xgb  = (const char*)xg + (size_t)n * PHW * PHW * 256;
    const char* wb2b = (const char*)wb2;

    // ---- stage B halo once: 18 rows x (18 px * 256B) = 5184 chunks of 16B, linear LDS
    #pragma unroll 1
    for (int i = 0; i < 11; ++i) {
        int c = i * 512 + tid;
        if (c < 5184) {
            int r = c / 288;
            int t = c - r * 288;
            gload16(xgb + ((size_t)(Y0 + r) * PHW + X0) * 256 + t * 16,
                    smem + 65536 + (i * 512 + wid * 64) * 16);
        }
    }

    // ---- A staging: 32KB per K-step, 4 chunks/thread
    auto stageA = [&](int k, int p) {
        const char* aS = wb2b + k * 32768;
        char* buf = smem + (p << 15);
        #pragma unroll
        for (int r = 0; r < 4; ++r)
            gload16(aS + (r * 512 + tid) * 16, buf + (r * 512 + wid * 64) * 16);
    };

    f32x4 acc[8][4];
    #pragma unroll
    for (int f = 0; f < 8; ++f)
        #pragma unroll
        for (int b = 0; b < 4; ++b) acc[f][b] = (f32x4)0.f;

    stageA(0, 0);
    stageA(1, 1);

    #pragma unroll 1
    for (int t = 0; t < 18; ++t) {
        const int p   = t & 1;
        const int tap = t >> 1;
        const int h   = t & 1;
        const int ky  = tap / 3;
        const int kx  = tap - ky * 3;
        const char* bA = smem + (p << 15);

        if (t < 17) { asm volatile("s_waitcnt vmcnt(4)" ::: "memory"); }
        else        { asm volatile("s_waitcnt vmcnt(0)" ::: "memory"); }
        BARRIER();   // A tile t resident for all waves (B resident since prologue)

        auto ldA = [&](int f, int kc) -> short8 {
            return *reinterpret_cast<const short8*>(bA + (((kc << 4) + mbase + f) << 10) + (lane << 4));
        };
        auto ldB = [&](int b, int kc) -> short8 {
            int R = pbase + b + ky;
            int C = l16 + kx;
            int icoff = (h << 7) + (kc << 6) + (lhi << 4);
            return *reinterpret_cast<const short8*>(
                smem + 65536 + (R * 18 + C) * 256 + (icoff ^ ((C & 7) << 4)));
        };

        #pragma unroll
        for (int kc = 0; kc < 2; ++kc) {
            short8 Af[8], Bf[4];
            #pragma unroll
            for (int f = 0; f < 8; ++f) Af[f] = ldA(f, kc);
            #pragma unroll
            for (int b = 0; b < 4; ++b) Bf[b] = ldB(b, kc);
            __builtin_amdgcn_s_setprio(1);
            #pragma unroll
            for (int f = 0; f < 8; ++f)
                #pragma unroll
                for (int b = 0; b < 4; ++b) MM(acc[f][b], Af[f], Bf[b]);
            __builtin_amdgcn_s_setprio(0);
        }

        BARRIER();   // all waves done reading A buf p
        if (t + 2 < 18) stageA(t + 2, p);
    }

    // ---- epilogue: M = wM*128 + f*16 + lhi*4 + r ; oc = M>>2, phase = M&3 = r
    #pragma unroll
    for (int f = 0; f < 8; ++f) {
        const int oc = wM * 32 + f * 4 + lhi;
        const float bi = bias[oc];
        #pragma unroll
        for (int b = 0; b < 4; ++b) {
            const int ypix = Y0 + pbase + b;
            const int xpix = X0 + l16;
            float* o0 = out + (((size_t)(n * OUT_C + oc) * OHW) + 2 * ypix) * OHW + 2 * xpix;
            float2 v0 = make_float2(postact(acc[f][b][0] + bi), postact(acc[f][b][1] + bi));
            float2 v1 = make_float2(postact(acc[f][b][2] + bi), postact(acc[f][b][3] + bi));
            *reinterpret_cast<float2*>(o0) = v0;
            *reinterpret_cast<float2*>(o0 + OHW) = v1;
        }
    }
}

// ================= fallback f32 path (round-1, verified) =================
__global__ void wprep_kernel(const float* __restrict__ w, float* __restrict__ wp) {
    int idx = blockIdx.x * blockDim.x + threadIdx.x;
    if (idx >= IN_C * 9 * 4 * OUT_C) return;
    int oc = idx & 63;
    int t  = idx >> 6;
    int ph = t & 3;  t >>= 2;
    int kx = t % 3;  t /= 3;
    int ky = t % 3;  t /= 3;
    int ic = t;
    int py = ph >> 1, px = ph & 1;
    int sy = 2 * ky + (py == 0 ? 1 : 0);
    int sx = 2 * kx + (px == 0 ? 1 : 0);
    const float k1[4] = {0.25f, 0.75f, 0.75f, 0.25f};
    float sum = 0.f;
    #pragma unroll
    for (int by = 0; by < 3; ++by) {
        int ay = sy - by;
        if (ay < 0 || ay > 3) continue;
        #pragma unroll
        for (int bx = 0; bx < 3; ++bx) {
            int ax = sx - bx;
            if (ax < 0 || ax > 3) continue;
            sum += w[((oc * IN_C + ic) * 3 + (2 - by)) * 3 + (2 - bx)] * k1[ay] * k1[ax];
        }
    }
    wp[idx] = sum * 0.029462782549439483f;
}

__global__ __launch_bounds__(256) void conv_main(
    const float* __restrict__ x, const float* __restrict__ gain,
    const float* __restrict__ wp, const float* __restrict__ bias,
    float* __restrict__ out) {
    const int n    = blockIdx.z >> 3;
    const int occ  = (blockIdx.z & 7) * 8;
    const int tx0  = blockIdx.x * 16;
    const int ty0  = blockIdx.y * 16;
    const int tid  = threadIdx.x;
    const int lx   = tid & 15;
    const int ly   = tid >> 4;
    __shared__ float xsf[8][18][18];
    float acc[4][8];
    #pragma unroll
    for (int p = 0; p < 4; ++p)
        #pragma unroll
        for (int o = 0; o < 8; ++o) acc[p][o] = 0.f;
    for (int ic0 = 0; ic0 < IN_C; ic0 += 8) {
        __syncthreads();
        for (int i = tid; i < 8 * 324; i += 256) {
            int icb = i / 324;
            int rem = i - icb * 324;
            int yy  = rem / 18;
            int xx  = rem - yy * 18;
            int gy  = ty0 + yy - 1;
            int gx  = tx0 + xx - 1;
            int ic  = ic0 + icb;
            float v = 0.f;
            if (gy >= 0 && gy < HW && gx >= 0 && gx < HW)
                v = x[((n * IN_C + ic) * HW + gy) * HW + gx] * gain[n * IN_C + ic];
            xsf[icb][yy][xx] = v;
        }
        __syncthreads();
        for (int icb = 0; icb < 8; ++icb) {
            const int ic = ic0 + icb;
            const float* wpp = wp + ic * (9 * 4 * OUT_C) + occ;
            #pragma unroll
            for (int ky = 0; ky < 3; ++ky)
                #pragma unroll
                for (int kx = 0; kx < 3; ++kx) {
                    float tv = xsf[icb][ly + ky][lx + kx];
                    const float* w9 = wpp + (ky * 3 + kx) * (4 * OUT_C);
                    #pragma unroll
                    for (int p = 0; p < 4; ++p)
                        #pragma unroll
                        for (int o = 0; o < 8; ++o)
                            acc[p][o] = fmaf(tv, w9[p * OUT_C + o], acc[p][o]);
                }
        }
    }
    const int ybase = 2 * (ty0 + ly);
    const int xbase = 2 * (tx0 + lx);
    #pragma unroll
    for (int o = 0; o < 8; ++o) {
        float b = bias[occ + o];
        #pragma unroll
        for (int py = 0; py < 2; ++py) {
            float2 v;
            v.x = postact(acc[py * 2 + 0][o] + b);
            v.y = postact(acc[py * 2 + 1][o] + b);
            *reinterpret_cast<float2*>(
                &out[((size_t)(n * OUT_C + occ + o) * OHW + (ybase + py)) * OHW + xbase]) = v;
        }
    }
}

extern "C" void kernel_launch(void* const* d_in, const int* in_sizes, int n_in,
                              void* d_out, int out_size, void* d_ws, size_t ws_size,
                              hipStream_t stream) {
    const float* x        = (const float*)d_in[0];
    const float* c        = (const float*)d_in[1];
    const float* weight   = (const float*)d_in[2];
    const float* bias     = (const float*)d_in[3];
    const float* w_affine = (const float*)d_in[4];
    const float* b_affine = (const float*)d_in[5];
    float* out = (float*)d_out;

    float* gain = (float*)d_ws;   // 4 KB @ 0

    const size_t NEED = 1048576 + (size_t)NB * PHW * PHW * IN_C * 2;  // ~35.7 MB
    if (ws_size >= NEED) {
        unsigned short* wb2 = (unsigned short*)((char*)d_ws + 8192);      // 589824 B
        unsigned short* xg  = (unsigned short*)((char*)d_ws + 1048576);   // 34.6 MB padded+swizzled NHWC
        gain_kernel<<<dim3((NB * IN_C * 64) / 256), dim3(256), 0, stream>>>(c, w_affine, b_affine, gain);
        wbprep2_kernel<<<dim3((18 * 16384) / 256), dim3(256), 0, stream>>>(weight, wb2);
        xprep_kernel<<<dim3(NB * HW), dim3(256), 0, stream>>>(x, gain, xg);
        border_kernel<<<dim3((NB * 516 * 16) / 256), dim3(256), 0, stream>>>(xg);
        conv_mfma3<<<dim3(512), dim3(512), 0, stream>>>(xg, wb2, bias, out);
    } else {
        float* wp = (float*)((char*)d_ws + 8192);
        gain_kernel<<<dim3((NB * IN_C * 64) / 256), dim3(256), 0, stream>>>(c, w_affine, b_affine, gain);
        wprep_kernel<<<dim3((IN_C * 9 * 4 * OUT_C + 255) / 256), dim3(256), 0, stream>>>(weight, wp);
        conv_main<<<dim3(HW / 16, HW / 16, NB * 8), dim3(256), 0, stream>>>(x, gain, wp, bias, out);
    }
}

// Round 5
// 105.079 us; speedup vs baseline: 25.0644x; 1.0624x over previous
//
#include <hip/hip_runtime.h>
#include <math.h>

#define IN_C   128
#define OUT_C  64
#define CDIM   512
#define HW     128   // input spatial (half-res)
#define PHW    130   // padded
#define OHW    256   // output spatial
#define NB     8     // batch

typedef __attribute__((ext_vector_type(8))) short short8;
typedef __attribute__((ext_vector_type(4))) float f32x4;

__device__ inline unsigned short f2bf(float f) {
    unsigned int u = __float_as_uint(f);
    unsigned int r = (u + 0x7fffu + ((u >> 16) & 1u)) >> 16;
    return (unsigned short)r;
}

__device__ inline float postact(float v) {
    v = v > 0.f ? v : 0.2f * v;
    v *= 1.4142135623730951f;
    return fminf(fmaxf(v, -256.f), 256.f);
}

__device__ __forceinline__ void gload16(const void* g, void* l) {
    __builtin_amdgcn_global_load_lds(
        (const __attribute__((address_space(1))) unsigned int*)g,
        (__attribute__((address_space(3))) unsigned int*)l, 16, 0, 0);
}

// ================= fused prep: wbprep (blocks 0..1151) + border (1152..1409) + gain (1410..1665)
// wb2 layout (A fragment-linear, PHASE-REGION-MAJOR):
//   flat = kt*16384 + pr*512 + lane*8 + e,  pr = hh*16 + kc*8 + wM*4 + fi
//   holds Wb[m][ic] for m = (wM*8 + hh*4 + fi)*16 + (lane&15),
//                       ic = (kt&1)*64 + kc*32 + (lane>>4)*8 + e,  tap = kt>>1
__global__ __launch_bounds__(256) void prep_kernel(
    const float* __restrict__ w, unsigned short* __restrict__ wb2,
    unsigned short* __restrict__ xg,
    const float* __restrict__ c, const float* __restrict__ wa,
    const float* __restrict__ ba, float* __restrict__ gain) {
    int blk = blockIdx.x;
    if (blk < 1152) {
        int idx  = blk * 256 + threadIdx.x;          // 18*16384 total
        int e    = idx & 7;
        int lane = (idx >> 3) & 63;
        int pr   = (idx >> 9) & 31;
        int kt   = idx >> 14;                        // 0..17
        int hh = pr >> 4, kcb = (pr >> 3) & 1, wM = (pr >> 2) & 1, fi = pr & 3;
        int m   = (wM * 8 + hh * 4 + fi) * 16 + (lane & 15);
        int ic  = (kt & 1) * 64 + kcb * 32 + (lane >> 4) * 8 + e;
        int tap = kt >> 1;
        int ky = tap / 3, kx = tap % 3;
        int oc = m >> 2, ph = m & 3;
        int py = ph >> 1, px = ph & 1;
        int sy = 2 * ky + (py == 0 ? 1 : 0);
        int sx = 2 * kx + (px == 0 ? 1 : 0);
        const float k1[4] = {0.25f, 0.75f, 0.75f, 0.25f};
        float sum = 0.f;
        #pragma unroll
        for (int by = 0; by < 3; ++by) {
            int ay = sy - by;
            if (ay < 0 || ay > 3) continue;
            #pragma unroll
            for (int bx = 0; bx < 3; ++bx) {
                int ax = sx - bx;
                if (ax < 0 || ax > 3) continue;
                sum += w[((oc * IN_C + ic) * 3 + (2 - by)) * 3 + (2 - bx)] * k1[ay] * k1[ax];
            }
        }
        wb2[idx] = f2bf(sum * 0.029462782549439483f);   // 1/sqrt(1152)
    } else if (blk < 1410) {
        int id = (blk - 1152) * 256 + threadIdx.x;   // 8*516*16 = 66048 exact
        int cc = id & 15;
        int t  = id >> 4;
        int p  = t % 516;
        int n  = t / 516;
        int Y, X;
        if (p < 130)      { Y = 0;   X = p; }
        else if (p < 260) { Y = 129; X = p - 130; }
        else              { int q = p - 260; Y = 1 + (q >> 1); X = (q & 1) * 129; }
        uint4 z = make_uint4(0, 0, 0, 0);
        *reinterpret_cast<uint4*>(xg + (((size_t)(n * PHW) + Y) * PHW + X) * 128 + cc * 8) = z;
    } else {
        int wave = (blk - 1410) * 4 + (threadIdx.x >> 6);   // 0..1023
        int lane = threadIdx.x & 63;
        int n  = wave >> 7;
        int ic = wave & 127;
        const float* cp = c + n * CDIM;
        const float* wp = wa + ic * CDIM;
        float s = 0.f;
        #pragma unroll
        for (int k = 0; k < CDIM / 64; ++k) s += cp[lane + 64 * k] * wp[lane + 64 * k];
        #pragma unroll
        for (int off = 32; off > 0; off >>= 1) s += __shfl_down(s, off);
        if (lane == 0) {
            float y = s * 0.04419417382415922f + ba[ic];
            gain[n * IN_C + ic] = 1.0f + tanhf(y);
        }
    }
}

// ---------------- xprep: padded 130x130 NHWC bf16, 16B-chunk order XOR-swizzled by (X&7)
__global__ __launch_bounds__(256) void xprep_kernel(const float* __restrict__ x,
                                                    const float* __restrict__ gain,
                                                    unsigned short* __restrict__ xg) {
    int n = blockIdx.x >> 7;
    int y = blockIdx.x & 127;
    __shared__ unsigned short lds[128][130];
    int tid = threadIdx.x;
    for (int i = tid; i < 128 * 128; i += 256) {
        int ic = i >> 7, pix = i & 127;
        float v = x[(((n * IN_C + ic) * HW) + y) * HW + pix] * gain[n * IN_C + ic];
        lds[pix][ic] = f2bf(v);
    }
    __syncthreads();
    unsigned int* dst = (unsigned int*)(xg + (((size_t)(n * PHW) + y + 1) * PHW + 1) * 128);
    for (int i = tid; i < 8192; i += 256) {
        int pix = i >> 6, d = i & 63;
        int j = d >> 2, ww = d & 3;
        int js = j ^ ((pix + 1) & 7);          // swizzle key = padded X & 7
        dst[pix * 64 + js * 4 + ww] = *reinterpret_cast<const unsigned int*>(&lds[pix][d * 2]);
    }
}

// ---------------- main conv: M=256 x N=256px x K=1152. B halo (18x18x128bf16) LDS-resident,
// A double-buffered 2x32KB (region-major). 4-phase interleaved schedule per K-step.
#define BARRIER() do { __builtin_amdgcn_sched_barrier(0); __builtin_amdgcn_s_barrier(); __builtin_amdgcn_sched_barrier(0); } while (0)
#define MM(ACC, AF, BF) ACC = __builtin_amdgcn_mfma_f32_16x16x32_bf16(AF, BF, ACC, 0, 0, 0)

__global__ __launch_bounds__(512, 2) void conv_mfma4(
    const unsigned short* __restrict__ xg,
    const unsigned short* __restrict__ wb2,
    const float* __restrict__ bias,
    float* __restrict__ out) {
    // A dbuf: [0, 65536) ; B halo: [65536, 65536+82944)
    __shared__ __align__(16) char smem[148480];

    const int bid = blockIdx.x;                 // 512 blocks; bijective XCD swizzle (512%8==0)
    const int wg  = ((bid & 7) << 6) + (bid >> 3);
    const int n     = wg >> 6;
    const int patch = wg & 63;
    const int Y0 = (patch >> 3) * 16;
    const int X0 = (patch & 7) * 16;            // mult of 8 -> swizzle key block-independent
    const int tid  = threadIdx.x;
    const int lane = tid & 63;
    const int wid  = tid >> 6;
    const int wM = wid >> 2;                    // 0..1
    const int wN = wid & 3;                     // 0..3
    const int l16 = lane & 15;
    const int lhi = lane >> 4;
    const int pbase = wN * 4;

    const char* xgb = (const char*)xg + (size_t)n * PHW * PHW * 256;
    const char* wbb = (const char*)wb2;
    char* haloB = smem + 65536;

    // ---- stage B halo once: 18 rows x 18 px x 256B = 5184 chunks of 16B, linear LDS
    #pragma unroll 1
    for (int i = 0; i < 11; ++i) {
        int cc = i * 512 + tid;
        if (cc < 5184) {
            int r = cc / 288;
            int t2 = cc - r * 288;
            gload16(xgb + ((size_t)(Y0 + r) * PHW + X0) * 256 + t2 * 16,
                    haloB + (i * 512 + wid * 64) * 16);
        }
    }

    // A staging: one 8KB half-region per call (1 gload16/thread)
    auto stageA = [&](int k, int hh, int half) {
        gload16(wbb + k * 32768 + hh * 16384 + half * 8192 + tid * 16,
                smem + ((k & 1) << 15) + hh * 16384 + half * 8192 + wid * 1024);
    };

    f32x4 acc[8][4];
    #pragma unroll
    for (int f = 0; f < 8; ++f)
        #pragma unroll
        for (int b = 0; b < 4; ++b) acc[f][b] = (f32x4)0.f;

    // prologue: fh0(0), fh1(0), fh0(1)   (fh1(1) comes from step 0 P0/P1)
    stageA(0, 0, 0); stageA(0, 0, 1);
    stageA(0, 1, 0); stageA(0, 1, 1);
    stageA(1, 0, 0); stageA(1, 0, 1);
    asm volatile("s_waitcnt vmcnt(4)" ::: "memory");   // fh0(0) landed (mine)
    BARRIER();                                          // ...and everyone's

    #pragma unroll 1
    for (int t = 0; t < 18; ++t) {
        const char* bA = smem + ((t & 1) << 15);
        const int tap = t >> 1;
        const int h   = t & 1;
        const int ky  = tap / 3;
        const int kx  = tap - ky * 3;
        const int C   = l16 + kx;
        const int bswz = (C & 7) << 4;

        auto ldB1 = [&](int b, int kc) -> short8 {
            int icoff = ((h << 7) + (kc << 6) + (lhi << 4)) ^ bswz;
            return *reinterpret_cast<const short8*>(
                haloB + ((pbase + b + ky) * 18 + C) * 256 + icoff);
        };

        short8 Af[8], Bf0[4], Bf1[4];

        // ---- P0: reads A(fh0) + B(bh0); stage fh1(t+1).a
        #pragma unroll
        for (int f = 0; f < 4; ++f)
            #pragma unroll
            for (int kc = 0; kc < 2; ++kc)
                Af[f * 2 + kc] = *reinterpret_cast<const short8*>(
                    bA + ((kc * 8 + wM * 4 + f) << 10) + (lane << 4));
        #pragma unroll
        for (int b = 0; b < 2; ++b)
            #pragma unroll
            for (int kc = 0; kc < 2; ++kc) Bf0[b * 2 + kc] = ldB1(b, kc);
        if (t + 1 < 18) stageA(t + 1, 1, 0);
        BARRIER();
        __builtin_amdgcn_s_setprio(1);
        #pragma unroll
        for (int f = 0; f < 4; ++f)
            #pragma unroll
            for (int b = 0; b < 2; ++b) {
                MM(acc[f][b], Af[f * 2 + 0], Bf0[b * 2 + 0]);
                MM(acc[f][b], Af[f * 2 + 1], Bf0[b * 2 + 1]);
            }
        __builtin_amdgcn_s_setprio(0);

        // ---- P1: reads B(bh1); stage fh1(t+1).b; vmcnt guards fh1(t)
        #pragma unroll
        for (int b = 0; b < 2; ++b)
            #pragma unroll
            for (int kc = 0; kc < 2; ++kc) Bf1[b * 2 + kc] = ldB1(b + 2, kc);
        if (t + 1 < 18) stageA(t + 1, 1, 1);
        if (t < 17) { asm volatile("s_waitcnt vmcnt(4)" ::: "memory"); }
        else        { asm volatile("s_waitcnt vmcnt(0)" ::: "memory"); }
        BARRIER();
        __builtin_amdgcn_s_setprio(1);
        #pragma unroll
        for (int f = 0; f < 4; ++f)
            #pragma unroll
            for (int b = 0; b < 2; ++b) {
                MM(acc[f][b + 2], Af[f * 2 + 0], Bf1[b * 2 + 0]);
                MM(acc[f][b + 2], Af[f * 2 + 1], Bf1[b * 2 + 1]);
            }
        __builtin_amdgcn_s_setprio(0);

        // ---- P2: reads A(fh1) (reuse Af regs); stage fh0(t+2).a
        #pragma unroll
        for (int f = 0; f < 4; ++f)
            #pragma unroll
            for (int kc = 0; kc < 2; ++kc)
                Af[f * 2 + kc] = *reinterpret_cast<const short8*>(
                    bA + ((16 + kc * 8 + wM * 4 + f) << 10) + (lane << 4));
        if (t + 2 < 18) stageA(t + 2, 0, 0);
        BARRIER();
        __builtin_amdgcn_s_setprio(1);
        #pragma unroll
        for (int f = 0; f < 4; ++f)
            #pragma unroll
            for (int b = 0; b < 2; ++b) {
                MM(acc[4 + f][b], Af[f * 2 + 0], Bf0[b * 2 + 0]);
                MM(acc[4 + f][b], Af[f * 2 + 1], Bf0[b * 2 + 1]);
            }
        __builtin_amdgcn_s_setprio(0);

        // ---- P3: stage fh0(t+2).b; vmcnt guards fh0(t+1)
        if (t + 2 < 18) stageA(t + 2, 0, 1);
        if (t < 16)       { asm volatile("s_waitcnt vmcnt(4)" ::: "memory"); }
        else if (t == 16) { asm volatile("s_waitcnt vmcnt(2)" ::: "memory"); }
        BARRIER();
        __builtin_amdgcn_s_setprio(1);
        #pragma unroll
        for (int f = 0; f < 4; ++f)
            #pragma unroll
            for (int b = 0; b < 2; ++b) {
                MM(acc[4 + f][b + 2], Af[f * 2 + 0], Bf1[b * 2 + 0]);
                MM(acc[4 + f][b + 2], Af[f * 2 + 1], Bf1[b * 2 + 1]);
            }
        __builtin_amdgcn_s_setprio(0);
    }

    // ---- epilogue: M = wM*128 + f*16 + lhi*4 + r ; oc = M>>2, phase = M&3 = r
    #pragma unroll
    for (int f = 0; f < 8; ++f) {
        const int oc = wM * 32 + f * 4 + lhi;
        const float bi = bias[oc];
        #pragma unroll
        for (int b = 0; b < 4; ++b) {
            const int ypix = Y0 + pbase + b;
            const int xpix = X0 + l16;
            float* o0 = out + (((size_t)(n * OUT_C + oc) * OHW) + 2 * ypix) * OHW + 2 * xpix;
            float2 v0 = make_float2(postact(acc[f][b][0] + bi), postact(acc[f][b][1] + bi));
            float2 v1 = make_float2(postact(acc[f][b][2] + bi), postact(acc[f][b][3] + bi));
            *reinterpret_cast<float2*>(o0) = v0;
            *reinterpret_cast<float2*>(o0 + OHW) = v1;
        }
    }
}

// ================= fallback f32 path (round-1, verified) =================
__global__ void gain_kernel(const float* __restrict__ c,
                            const float* __restrict__ w_affine,
                            const float* __restrict__ b_affine,
                            float* __restrict__ gain) {
    int wave = (blockIdx.x * blockDim.x + threadIdx.x) >> 6;
    int lane = threadIdx.x & 63;
    if (wave >= NB * IN_C) return;
    int n  = wave >> 7;
    int ic = wave & 127;
    const float* cp = c + n * CDIM;
    const float* wp = w_affine + ic * CDIM;
    float s = 0.f;
    #pragma unroll
    for (int k = 0; k < CDIM / 64; ++k) s += cp[lane + 64 * k] * wp[lane + 64 * k];
    #pragma unroll
    for (int off = 32; off > 0; off >>= 1) s += __shfl_down(s, off);
    if (lane == 0) {
        float y = s * 0.04419417382415922f + b_affine[ic];
        gain[n * IN_C + ic] = 1.0f + tanhf(y);
    }
}

__global__ void wprep_kernel(const float* __restrict__ w, float* __restrict__ wp) {
    int idx = blockIdx.x * blockDim.x + threadIdx.x;
    if (idx >= IN_C * 9 * 4 * OUT_C) return;
    int oc = idx & 63;
    int t  = idx >> 6;
    int ph = t & 3;  t >>= 2;
    int kx = t % 3;  t /= 3;
    int ky = t % 3;  t /= 3;
    int ic = t;
    int py = ph >> 1, px = ph & 1;
    int sy = 2 * ky + (py == 0 ? 1 : 0);
    int sx = 2 * kx + (px == 0 ? 1 : 0);
    const float k1[4] = {0.25f, 0.75f, 0.75f, 0.25f};
    float sum = 0.f;
    #pragma unroll
    for (int by = 0; by < 3; ++by) {
        int ay = sy - by;
        if (ay < 0 || ay > 3) continue;
        #pragma unroll
        for (int bx = 0; bx < 3; ++bx) {
            int ax = sx - bx;
            if (ax < 0 || ax > 3) continue;
            sum += w[((oc * IN_C + ic) * 3 + (2 - by)) * 3 + (2 - bx)] * k1[ay] * k1[ax];
        }
    }
    wp[idx] = sum * 0.029462782549439483f;
}

__global__ __launch_bounds__(256) void conv_main(
    const float* __restrict__ x, const float* __restrict__ gain,
    const float* __restrict__ wp, const float* __restrict__ bias,
    float* __restrict__ out) {
    const int n    = blockIdx.z >> 3;
    const int occ  = (blockIdx.z & 7) * 8;
    const int tx0  = blockIdx.x * 16;
    const int ty0  = blockIdx.y * 16;
    const int tid  = threadIdx.x;
    const int lx   = tid & 15;
    const int ly   = tid >> 4;
    __shared__ float xsf[8][18][18];
    float acc[4][8];
    #pragma unroll
    for (int p = 0; p < 4; ++p)
        #pragma unroll
        for (int o = 0; o < 8; ++o) acc[p][o] = 0.f;
    for (int ic0 = 0; ic0 < IN_C; ic0 += 8) {
        __syncthreads();
        for (int i = tid; i < 8 * 324; i += 256) {
            int icb = i / 324;
            int rem = i - icb * 324;
            int yy  = rem / 18;
            int xx  = rem - yy * 18;
            int gy  = ty0 + yy - 1;
            int gx  = tx0 + xx - 1;
            int ic  = ic0 + icb;
            float v = 0.f;
            if (gy >= 0 && gy < HW && gx >= 0 && gx < HW)
                v = x[((n * IN_C + ic) * HW + gy) * HW + gx] * gain[n * IN_C + ic];
            xsf[icb][yy][xx] = v;
        }
        __syncthreads();
        for (int icb = 0; icb < 8; ++icb) {
            const int ic = ic0 + icb;
            const float* wpp = wp + ic * (9 * 4 * OUT_C) + occ;
            #pragma unroll
            for (int ky = 0; ky < 3; ++ky)
                #pragma unroll
                for (int kx = 0; kx < 3; ++kx) {
                    float tv = xsf[icb][ly + ky][lx + kx];
                    const float* w9 = wpp + (ky * 3 + kx) * (4 * OUT_C);
                    #pragma unroll
                    for (int p = 0; p < 4; ++p)
                        #pragma unroll
                        for (int o = 0; o < 8; ++o)
                            acc[p][o] = fmaf(tv, w9[p * OUT_C + o], acc[p][o]);
                }
        }
    }
    const int ybase = 2 * (ty0 + ly);
    const int xbase = 2 * (tx0 + lx);
    #pragma unroll
    for (int o = 0; o < 8; ++o) {
        float b = bias[occ + o];
        #pragma unroll
        for (int py = 0; py < 2; ++py) {
            float2 v;
            v.x = postact(acc[py * 2 + 0][o] + b);
            v.y = postact(acc[py * 2 + 1][o] + b);
            *reinterpret_cast<float2*>(
                &out[((size_t)(n * OUT_C + occ + o) * OHW + (ybase + py)) * OHW + xbase]) = v;
        }
    }
}

extern "C" void kernel_launch(void* const* d_in, const int* in_sizes, int n_in,
                              void* d_out, int out_size, void* d_ws, size_t ws_size,
                              hipStream_t stream) {
    const float* x        = (const float*)d_in[0];
    const float* c        = (const float*)d_in[1];
    const float* weight   = (const float*)d_in[2];
    const float* bias     = (const float*)d_in[3];
    const float* w_affine = (const float*)d_in[4];
    const float* b_affine = (const float*)d_in[5];
    float* out = (float*)d_out;

    float* gain = (float*)d_ws;   // 4 KB @ 0

    const size_t NEED = 1048576 + (size_t)NB * PHW * PHW * IN_C * 2;  // ~35.7 MB
    if (ws_size >= NEED) {
        unsigned short* wb2 = (unsigned short*)((char*)d_ws + 8192);      // 589824 B
        unsigned short* xg  = (unsigned short*)((char*)d_ws + 1048576);   // 34.6 MB padded+swizzled NHWC
        prep_kernel<<<dim3(1666), dim3(256), 0, stream>>>(weight, wb2, xg, c, w_affine, b_affine, gain);
        xprep_kernel<<<dim3(NB * HW), dim3(256), 0, stream>>>(x, gain, xg);
        conv_mfma4<<<dim3(512), dim3(512), 0, stream>>>(xg, wb2, bias, out);
    } else {
        float* wp = (float*)((char*)d_ws + 8192);
        gain_kernel<<<dim3((NB * IN_C * 64) / 256), dim3(256), 0, stream>>>(c, w_affine, b_affine, gain);
        wprep_kernel<<<dim3((IN_C * 9 * 4 * OUT_C + 255) / 256), dim3(256), 0, stream>>>(weight, wp);
        conv_main<<<dim3(HW / 16, HW / 16, NB * 8), dim3(256), 0, stream>>>(x, gain, wp, bias, out);
    }
}